// Round 15
// baseline (1430.123 us; speedup 1.0000x reference)
//
#include <hip/hip_runtime.h>
#include <hip/hip_bf16.h>
#include <cstdint>

#define T_LEN 512
#define BATCH 128
#define EMBD 256
#define NCLS 25
#define PADTOK 1
#define CHUNK 64
#define NCHUNK 8

#define N_WPERM (2*4*16*8*64*8)   /* 524288: wih bf16 elems / whh fp8 bytes */
#define N_WE (2*2*8*64*8)         /* 16384 fp8 bytes */
#define N_BIAS (2*1024)

typedef float f32x4 __attribute__((ext_vector_type(4)));
typedef short s16x8 __attribute__((ext_vector_type(8)));
typedef unsigned int u32x4 __attribute__((ext_vector_type(4)));

#define INV1024 (0.0009765625f)
#define LOG2E 1.4426950408889634f
#define INV1024_LOG2E (1.4426950408889634f/1024.f)
#define NEG2LOG2E (-2.8853900817779268f)

__device__ __forceinline__ unsigned short f2bf(float f) {
  unsigned int u = __builtin_bit_cast(unsigned int, f);
  unsigned int r = (u + 0x7FFFu + ((u >> 16) & 1u)) >> 16;
  return (unsigned short)r;
}
__device__ __forceinline__ float bf2f(unsigned short h) {
  unsigned int u = ((unsigned int)h) << 16;
  return __builtin_bit_cast(float, u);
}
__device__ __forceinline__ unsigned char f2fp8(float v) {
  int pk = __builtin_amdgcn_cvt_pk_fp8_f32(v, v, 0, false);
  return (unsigned char)(pk & 0xFF);
}
// fast sigmoid/tanh helpers: input already in log2 domain (x2 = x*log2e)
__device__ __forceinline__ float sig2(float x2) {
  return __builtin_amdgcn_rcpf(1.f + __builtin_amdgcn_exp2f(-x2));
}
__device__ __forceinline__ float tanh2(float x2) {   // tanh(x) from x2=x*log2e
  return 2.f*__builtin_amdgcn_rcpf(1.f + __builtin_amdgcn_exp2f(-2.f*x2)) - 1.f;
}

// ---------------- prep: fragment-order weight permutes + bias sum ----------
__global__ void prep_kernel(const float* wih_f, const float* whh_f,
                            const float* bih_f, const float* bhh_f,
                            const float* wih_b, const float* whh_b,
                            const float* bih_b, const float* bhh_b,
                            const float* W_e,
                            unsigned short* wih_p, unsigned char* whh_p,
                            unsigned char* we_p, float* bias)
{
  long total = 2L*N_WPERM + N_WE + N_BIAS;
  for (long i = (long)blockIdx.x*blockDim.x + threadIdx.x; i < total;
       i += (long)gridDim.x*blockDim.x) {
    long j = i;
    if (j < N_WPERM) {           // wih, bf16, 4-wave layout
      int o = (int)j;
      int e = o & 7, l = (o>>3)&63, s = (o>>9)&15, kt = (o>>13)&7, w = (o>>16)&3, d = (o>>18)&1;
      int n = (s>>2)*256 + w*64 + (s&3)*16 + (l & 15);
      int kk = kt*32 + (l>>4)*8 + e;
      const float* src = d ? wih_b : wih_f;
      wih_p[o] = f2bf(src[n*256 + kk]);
      continue;
    }
    j -= N_WPERM;
    if (j < N_WPERM) {           // whh, fp8 scale 64, 8-wave layout
      int o = (int)j;
      int e = o & 7, l = (o>>3)&63, s = (o>>9)&7, kt = (o>>12)&7, w = (o>>15)&7, d = (o>>18)&1;
      int n = (s>>1)*256 + w*32 + (s&1)*16 + (l & 15);
      int kk = kt*32 + (l>>4)*8 + e;
      const float* src = d ? whh_b : whh_f;
      whh_p[o] = f2fp8(src[n*256 + kk] * 64.f);
      continue;
    }
    j -= N_WPERM;
    if (j < N_WE) {              // W_e, fp8 scale 64
      int o = (int)j;
      int e = o&7, l = (o>>3)&63, kt = (o>>9)&7, nt = (o>>12)&1, dp = (o>>13)&1;
      int cc = nt*16 + (l&15);
      int kk = dp*256 + kt*32 + (l>>4)*8 + e;
      we_p[o] = (cc < NCLS) ? f2fp8(W_e[cc*512 + kk] * 64.f) : (unsigned char)0;
      continue;
    }
    j -= N_WE;
    { int o = (int)j; int d = o>>10; int g = o & 1023;
      bias[o] = d ? (bih_b[g]+bhh_b[g]) : (bih_f[g]+bhh_f[g]); }
  }
}

// ------- xg body: (emb[sent] @ W_ih^T + biases) * log2e, permuted bf16 -----
__device__ __forceinline__ void xg_body(const int* sent, const float* emb,
    const unsigned short* wih_p, const float* bias, unsigned short* xg,
    int k, int blk2, int tid)
{
  int d = blk2 >> 8;
  int blk = blk2 & 255;
  int u = blk >> 2, q = blk & 3;
  int ss = k*CHUNK + u;
  int t = d ? (T_LEN-1-ss) : ss;
  int w = tid >> 6, l = tid & 63, lg = l >> 4, lm = l & 15;

  int tok0 = sent[t*BATCH + q*32 + lm];
  int tok1 = sent[t*BATCH + q*32 + 16 + lm];

  const char* wbase = (const char*)wih_p + ((long)(d*4 + w) << 17);

  f32x4 acc[2][16] = {};
  for (int kt = 0; kt < 8; ++kt) {
    const float* p0 = emb + (long)tok0*256 + kt*32 + lg*8;
    const float* p1 = emb + (long)tok1*256 + kt*32 + lg*8;
    f32x4 q00 = *(const f32x4*)p0, q01 = *(const f32x4*)(p0+4);
    f32x4 q10 = *(const f32x4*)p1, q11 = *(const f32x4*)(p1+4);
    s16x8 a0, a1;
    #pragma unroll
    for (int e = 0; e < 4; ++e) {
      a0[e]   = (short)f2bf(q00[e]); a0[4+e] = (short)f2bf(q01[e]);
      a1[e]   = (short)f2bf(q10[e]); a1[4+e] = (short)f2bf(q11[e]);
    }
    #pragma unroll
    for (int s = 0; s < 16; ++s) {
      s16x8 bf = *(const s16x8*)(wbase + (((kt*16 + s) << 10) + (l << 4)));
      acc[0][s] = __builtin_amdgcn_mfma_f32_16x16x32_bf16(a0, bf, acc[0][s], 0,0,0);
      acc[1][s] = __builtin_amdgcn_mfma_f32_16x16x32_bf16(a1, bf, acc[1][s], 0,0,0);
    }
  }
  float bsv[16];
  #pragma unroll
  for (int s = 0; s < 16; ++s) {
    int n = (s>>2)*256 + w*64 + (s&3)*16 + lm;
    bsv[s] = bias[d*1024 + n];
  }
  #pragma unroll
  for (int mt = 0; mt < 2; ++mt) {
    int nb = q*2 + mt;
    char* base = (char*)xg + (((((long)d*CHUNK + u)*8 + nb)*4 + w)*64 + l)*128;
    #pragma unroll
    for (int qq = 0; qq < 8; ++qq) {
      u32x4 pk;
      #pragma unroll
      for (int h2 = 0; h2 < 4; ++h2) {
        int j0 = qq*8 + h2*2;
        unsigned short v0 = f2bf((acc[mt][j0>>2][j0&3] + bsv[j0>>2]) * LOG2E);
        unsigned short v1 = f2bf((acc[mt][(j0+1)>>2][(j0+1)&3] + bsv[(j0+1)>>2]) * LOG2E);
        pk[h2] = (unsigned)v0 | ((unsigned)v1 << 16);
      }
      *(u32x4*)(base + qq*16) = pk;
    }
  }
}

// standalone xg (prologue chunk 0 + sequential fallback)
__global__ __launch_bounds__(256) void xg_kernel(const int* sent, const float* emb,
    const unsigned short* wih_p, const float* bias, unsigned short* xg, int k)
{
  xg_body(sent, emb, wih_p, bias, xg, k, blockIdx.y*256 + blockIdx.x, threadIdx.x);
}

// ---------------- fused: lstm chunk k (blocks 0-15) + xg chunk k+1 ---------
// lstm: h double-buffered in LDS (ONE barrier/step); xg operand prefetched a
// full step ahead so neither its load latency nor the emission-store drain
// sits on the recurrence chain.
__global__ __launch_bounds__(512, 1) void fused_kernel(
    const int* sent, const float* emb, const unsigned short* wih_p, const float* bias,
    const unsigned short* xg_rd, unsigned short* xg_wr,
    const unsigned char* whh_p, const unsigned char* we_p,
    float* emis_f, float* emis_b, unsigned char* hsave, float* csave, int k)
{
  if (blockIdx.x >= 16) {
    if (threadIdx.x < 256 && k + 1 < NCHUNK)
      xg_body(sent, emb, wih_p, bias, xg_wr, k + 1, blockIdx.x - 16, threadIdx.x);
    return;
  }

  __shared__ char h_lds[8192];     // 2 x 4KB fp8 h buffers, XOR-swizzled
  __shared__ char we_lds[8192];    // emission weights for this direction

  int id = blockIdx.x, d = id >> 3, nb = id & 7, bbase = nb*16;
  int w = threadIdx.x >> 6, l = threadIdx.x & 63, lg = l >> 4, lm = l & 15;
  float* emis = d ? emis_b : emis_f;
  bool ewave = (w == 0) || (w == 2);   // emission on SIMD0 and SIMD2
  int nt = w >> 1;

  // stage emission weights (8 KB, once)
  ((u32x4*)we_lds)[threadIdx.x] = ((const u32x4*)we_p)[d*512 + threadIdx.x];

  // whole W_hh slice in registers: 64 frags x (8 fp8) = 128 VGPRs
  long wreg[64];
  const char* wbase = (const char*)whh_p + ((long)(d*8 + w) << 15);
  #pragma unroll
  for (int i = 0; i < 64; ++i)
    wreg[i] = *(const long*)(wbase + (i << 9) + (l << 3));

  float c[8];
  if (k == 0) {
    for (int i = threadIdx.x; i < 2048; i += 512) ((unsigned*)h_lds)[i] = 0u;
    #pragma unroll
    for (int i = 0; i < 8; ++i) c[i] = 0.f;
  } else {
    // restore h into buffer 1 (read-buffer of step u=0)
    u32x4* hl = (u32x4*)(h_lds + 4096);
    const u32x4* hs = (const u32x4*)(hsave + (long)id*4096);
    if (threadIdx.x < 256) hl[threadIdx.x] = hs[threadIdx.x];
    const float* cs = csave + ((long)id*512 + threadIdx.x)*8;
    #pragma unroll
    for (int i = 0; i < 8; ++i) c[i] = cs[i];
  }
  __syncthreads();

  int prev_t = (k == 0) ? -1 : (d ? (T_LEN - k*CHUNK) : (k*CHUNK - 1));

  // xv prefetch: load step-0 operand now
  #define XB(u) ((const char*)xg_rd \
      + (((((long)d*CHUNK + (u))*8 + nb)*4 + (w>>1))*64 + l)*128 + ((w&1)*16))
  u32x4 xv_cur[4], xv_nxt[4];
  {
    const char* xb = XB(0);
    #pragma unroll
    for (int i = 0; i < 4; ++i) xv_cur[i] = *(const u32x4*)(xb + i*32);
  }

  for (int u = 0; u < CHUNK; ++u) {
    int ss = k*CHUNK + u;
    int t = d ? (T_LEN-1-ss) : ss;

    // single barrier: prev step's h writes (other buffer) now visible
    asm volatile("s_waitcnt lgkmcnt(0)" ::: "memory");
    __builtin_amdgcn_s_barrier();

    const char* hr = h_lds + (((u & 1) ^ 1) << 12);   // read buffer
    char*       hw = h_lds + ((u & 1) << 12);         // write buffer

    long a[8];
    #pragma unroll
    for (int kt = 0; kt < 8; ++kt) {
      int off = (lm*256 + kt*32 + lg*8) ^ ((lm&7)<<3);
      a[kt] = *(const long*)(hr + off);
    }

    // emissions MFMA for previous h (waves 0,2 -> SIMD0,SIMD2)
    f32x4 ea = {0.f,0.f,0.f,0.f};
    if (ewave && prev_t >= 0) {
      #pragma unroll
      for (int kt = 0; kt < 8; ++kt) {
        long ew = *(const long*)(we_lds + ((nt*8 + kt) << 9) + (l << 3));
        ea = __builtin_amdgcn_mfma_f32_16x16x32_fp8_fp8(a[kt], ew, ea, 0,0,0);
      }
    }

    // main matvec: all weights in registers
    f32x4 acc[8];
    #pragma unroll
    for (int s = 0; s < 8; ++s) acc[s] = (f32x4){0.f,0.f,0.f,0.f};
    #pragma unroll
    for (int kt = 0; kt < 8; ++kt)
      #pragma unroll
      for (int s = 0; s < 8; ++s)
        acc[s] = __builtin_amdgcn_mfma_f32_16x16x32_fp8_fp8(a[kt], wreg[kt*8+s], acc[s], 0,0,0);

    // emissions store (older than next-step loads in the vm queue; gets a
    // full step to drain before anything waits on that queue position)
    if (ewave && prev_t >= 0) {
      int cc = nt*16 + lm;
      if (cc < NCLS) {
        #pragma unroll
        for (int r = 0; r < 4; ++r)
          emis[((long)prev_t*BATCH + bbase + lg*4 + r)*NCLS + cc] = ea[r]*INV1024;
      }
    }

    // prefetch next step's xg operand (consumed next iteration)
    {
      int un = (u + 1 < CHUNK) ? (u + 1) : u;
      const char* xb = XB(un);
      #pragma unroll
      for (int i = 0; i < 4; ++i) xv_nxt[i] = *(const u32x4*)(xb + i*32);
    }

    // xg add; gates emerge in log2 domain (xg pre-scaled by log2e)
    #pragma unroll
    for (int s = 0; s < 8; ++s)
      #pragma unroll
      for (int r = 0; r < 4; ++r) {
        unsigned wd = xv_cur[s>>1][(s&1)*2 + (r>>1)];
        unsigned short us = (r&1) ? (unsigned short)(wd>>16) : (unsigned short)(wd & 0xffff);
        acc[s][r] = acc[s][r]*INV1024_LOG2E + bf2f(us);
      }

    // nonlinearities (log2-domain, hw rcp/exp2): i,f,g,o at s = q,2+q,4+q,6+q
    #pragma unroll
    for (int q = 0; q < 2; ++q)
      #pragma unroll
      for (int r = 0; r < 4; ++r) {
        float si = sig2(acc[q][r]);
        float sf = sig2(acc[2+q][r]);
        float tg = tanh2(acc[4+q][r]);
        float so = sig2(acc[6+q][r]);
        float cn = sf*c[q*4+r] + si*tg;
        c[q*4+r] = cn;
        float tc = 2.f*__builtin_amdgcn_rcpf(1.f + __builtin_amdgcn_exp2f(cn*NEG2LOG2E)) - 1.f;
        int m = lg*4 + r;
        int jj = w*32 + q*16 + lm;
        int off = (m*256 + jj) ^ ((m&7)<<3);
        *(unsigned char*)(hw + off) = f2fp8((so*16.f)*tc);
      }

    #pragma unroll
    for (int i = 0; i < 4; ++i) xv_cur[i] = xv_nxt[i];
    prev_t = t;
  }
  #undef XB

  asm volatile("s_waitcnt lgkmcnt(0)" ::: "memory");
  __builtin_amdgcn_s_barrier();
  // final h lives in buffer 1 (last write u=63 -> 63&1 = 1)

  if (k == NCHUNK-1) {
    if (ewave) {
      long a[8];
      #pragma unroll
      for (int kt = 0; kt < 8; ++kt) {
        int off = (lm*256 + kt*32 + lg*8) ^ ((lm&7)<<3);
        a[kt] = *(const long*)(h_lds + 4096 + off);
      }
      f32x4 ea = {0.f,0.f,0.f,0.f};
      #pragma unroll
      for (int kt = 0; kt < 8; ++kt) {
        long ew = *(const long*)(we_lds + ((nt*8 + kt) << 9) + (l << 3));
        ea = __builtin_amdgcn_mfma_f32_16x16x32_fp8_fp8(a[kt], ew, ea, 0,0,0);
      }
      int cc = nt*16 + lm;
      if (cc < NCLS) {
        #pragma unroll
        for (int r = 0; r < 4; ++r)
          emis[((long)prev_t*BATCH + bbase + lg*4 + r)*NCLS + cc] = ea[r]*INV1024;
      }
    }
  } else {
    u32x4* hl = (u32x4*)(h_lds + 4096);
    u32x4* hs = (u32x4*)(hsave + (long)id*4096);
    if (threadIdx.x < 256) hs[threadIdx.x] = hl[threadIdx.x];
    float* cs = csave + ((long)id*512 + threadIdx.x)*8;
    #pragma unroll
    for (int i = 0; i < 8; ++i) cs[i] = c[i];
  }
}

// ---------------- emissions fuse: emis_c = emis_f + emis_b + b_e ------------
__global__ __launch_bounds__(256) void efuse_kernel(const float* emis_f,
    const float* emis_b, const float* b_e, float* emis_c)
{
  int i = blockIdx.x*256 + threadIdx.x;
  if (i < T_LEN*BATCH*NCLS)
    emis_c[i] = emis_f[i] + emis_b[i] + b_e[i % NCLS];
}

// ---------------- CRF numerator -------------------------------------------
__global__ void num_kernel(const int* sent, const int* tags, const float* emis_c,
    const float* start_t, const float* end_t, const float* trans, float* num_buf)
{
  int b = blockIdx.x, l = threadIdx.x;   // 64 threads = 1 wave
  float acc = 0.f; int cnt = 0;
  for (int t = l; t < T_LEN; t += 64) {
    int tag = tags[t*BATCH + b];
    float E = emis_c[((long)t*BATCH+b)*NCLS + tag];
    int m = (sent[t*BATCH+b] != PADTOK) ? 1 : 0;
    cnt += m;
    if (t == 0) acc += start_t[tag] + E;
    else if (m) acc += trans[tags[(t-1)*BATCH + b]*NCLS + tag] + E;
  }
  #pragma unroll
  for (int off = 32; off; off >>= 1) { acc += __shfl_xor(acc, off); cnt += __shfl_xor(cnt, off); }
  if (l == 0) num_buf[b] = acc + end_t[tags[(cnt-1)*BATCH + b]];
}

// ---- CRF forward (denominator): readfirstlane ref + readlane/SGPR bcast ---
__global__ __launch_bounds__(64) void denom_kernel(const int* sent, const float* emis_c,
    const float* start_t, const float* end_t, const float* trans,
    const float* num_buf, float* llh)
{
  const float INVLN2 = 1.4426950408889634f;
  const float LN2 = 0.6931471805599453f;
  int l = threadIdx.x;
  bool valid = l < NCLS;
  int j = valid ? l : 0;
  int b = blockIdx.x;                     // 128 blocks, 1 row per wave

  float etr[NCLS];                        // E column j, linear domain
  #pragma unroll
  for (int i = 0; i < NCLS; ++i)
    etr[i] = __builtin_amdgcn_exp2f(trans[i*NCLS + j] * INVLN2);

  float S = (start_t[j] + emis_c[(long)b*NCLS + j]) * INVLN2;

  float e1 = emis_c[((long)1*BATCH + b)*NCLS + j];
  float e2 = emis_c[((long)2*BATCH + b)*NCLS + j];
  int m1 = sent[1*BATCH + b], m2 = sent[2*BATCH + b];

  for (int t = 1; t < T_LEN; ++t) {
    float e0 = e1; int m0 = m1;
    e1 = e2; m1 = m2;
    if (t + 2 < T_LEN) {
      e2 = emis_c[((long)(t+2)*BATCH + b)*NCLS + j];
      m2 = sent[(t+2)*BATCH + b];
    }
    float sref = __builtin_bit_cast(float,
        __builtin_amdgcn_readfirstlane(__builtin_bit_cast(int, S)));
    float qv = __builtin_amdgcn_exp2f(S - sref);
    float accs[5] = {0.f, 0.f, 0.f, 0.f, 0.f};
    #pragma unroll
    for (int i = 0; i < NCLS; ++i) {
      float qi = __builtin_bit_cast(float,
          __builtin_amdgcn_readlane(__builtin_bit_cast(int, qv), i));
      accs[i % 5] = fmaf(qi, etr[i], accs[i % 5]);
    }
    float dot = ((accs[0] + accs[1]) + (accs[2] + accs[3])) + accs[4];
    float nxt = sref + __builtin_amdgcn_logf(dot) + e0 * INVLN2;
    if (m0 != PADTOK) S = nxt;
  }

  float vf = valid ? (S + end_t[j] * INVLN2) : -1e30f;
  float mx = vf;
  #pragma unroll
  for (int off = 32; off; off >>= 1) mx = fmaxf(mx, __shfl_xor(mx, off));
  float ss = valid ? __builtin_amdgcn_exp2f(vf - mx) : 0.f;
  #pragma unroll
  for (int off = 32; off; off >>= 1) ss += __shfl_xor(ss, off);
  if (l == 0) llh[b] = num_buf[b] - (mx + __builtin_amdgcn_logf(ss)) * LN2;
}

__global__ void final_kernel(const float* llh, float* out) {
  __shared__ float red[2];
  int l = threadIdx.x;   // 128
  float v = llh[l];
  #pragma unroll
  for (int off = 32; off; off >>= 1) v += __shfl_xor(v, off);
  if ((l & 63) == 0) red[l >> 6] = v;
  __syncthreads();
  if (l == 0) out[0] = -(red[0] + red[1]);
}

extern "C" void kernel_launch(void* const* d_in, const int* in_sizes, int n_in,
                              void* d_out, int out_size, void* d_ws, size_t ws_size,
                              hipStream_t stream) {
  const int*   sent  = (const int*)d_in[0];
  const int*   tags  = (const int*)d_in[1];
  const float* emb   = (const float*)d_in[2];
  const float* wih_f = (const float*)d_in[3];
  const float* whh_f = (const float*)d_in[4];
  const float* bih_f = (const float*)d_in[5];
  const float* bhh_f = (const float*)d_in[6];
  const float* wih_b = (const float*)d_in[7];
  const float* whh_b = (const float*)d_in[8];
  const float* bih_b = (const float*)d_in[9];
  const float* bhh_b = (const float*)d_in[10];
  const float* W_e   = (const float*)d_in[11];
  const float* b_e   = (const float*)d_in[12];
  const float* st    = (const float*)d_in[13];
  const float* et    = (const float*)d_in[14];
  const float* tr    = (const float*)d_in[15];
  (void)in_sizes; (void)n_in; (void)out_size;

  const long SLOT = (long)2*CHUNK*BATCH*1024*2;   // 32 MiB per xg slot

  char* ws = (char*)d_ws;
  unsigned short* wih_p  = (unsigned short*)ws; ws += (long)N_WPERM*2;      // 1 MiB
  unsigned char*  whh_p  = (unsigned char*)ws;  ws += (long)N_WPERM;        // 512 KiB
  unsigned char*  we_p   = (unsigned char*)ws;  ws += (long)N_WE;           // 16 KiB
  float*          bias   = (float*)ws;          ws += (long)N_BIAS*4;       // 8 KiB
  unsigned short* xgr0   = (unsigned short*)ws; ws += SLOT;                 // 32 MiB
  float*          emis_f = (float*)ws;          ws += (long)T_LEN*BATCH*NCLS*4;
  float*          emis_b = (float*)ws;          ws += (long)T_LEN*BATCH*NCLS*4;
  unsigned char*  hsave  = (unsigned char*)ws;  ws += (long)16*4096;
  float*          csave  = (float*)ws;          ws += (long)16*512*8*4;
  float*          numb   = (float*)ws;          ws += 512;
  float*          llh    = (float*)ws;          ws += 512;
  unsigned short* xgr1   = (unsigned short*)ws; ws += SLOT;                 // 32 MiB (pipelined only)
  float*          emis_c = (float*)xgr0;        // alias: slots dead after last lstm

  bool pipelined = ws_size >= (size_t)((char*)ws - (char*)d_ws);

  prep_kernel<<<4168, 256, 0, stream>>>(wih_f, whh_f, bih_f, bhh_f,
                                        wih_b, whh_b, bih_b, bhh_b, W_e,
                                        wih_p, whh_p, we_p, bias);
  if (pipelined) {
    dim3 g1(256, 2);
    xg_kernel<<<g1, 256, 0, stream>>>(sent, emb, wih_p, bias, xgr0, 0);
    for (int k = 0; k < NCHUNK; ++k) {
      unsigned short* rd = (k & 1) ? xgr1 : xgr0;
      unsigned short* wr = (k & 1) ? xgr0 : xgr1;
      int grid = (k + 1 < NCHUNK) ? 528 : 16;
      fused_kernel<<<grid, 512, 0, stream>>>(sent, emb, wih_p, bias, rd, wr,
                                             whh_p, we_p, emis_f, emis_b, hsave, csave, k);
    }
  } else {
    for (int k = 0; k < NCHUNK; ++k) {
      dim3 g1(256, 2);
      xg_kernel<<<g1, 256, 0, stream>>>(sent, emb, wih_p, bias, xgr0, k);
      fused_kernel<<<16, 512, 0, stream>>>(sent, emb, wih_p, bias, xgr0, xgr0,
                                           whh_p, we_p, emis_f, emis_b, hsave, csave, k);
    }
  }
  efuse_kernel<<<(T_LEN*BATCH*NCLS + 255)/256, 256, 0, stream>>>(emis_f, emis_b, b_e, emis_c);
  num_kernel<<<128, 64, 0, stream>>>(sent, tags, emis_c, st, et, tr, numb);
  denom_kernel<<<128, 64, 0, stream>>>(sent, emis_c, st, et, tr, numb, llh);
  final_kernel<<<1, 128, 0, stream>>>(llh, (float*)d_out);
}